// Round 5
// baseline (402.487 us; speedup 1.0000x reference)
//
#include <hip/hip_runtime.h>

// BoostedNeuralLDPCDecoder — MI355X HIP implementation (round 5)
//
// SINGLE fused kernel: the batch axis b is fully separable (all reference ops
// are elementwise in b), so one 1024-thread workgroup per b runs all 5
// decode iterations with __syncthreads() between CN/VN phases. Eliminates
// 10 kernel launches + grid-wide drains that dominated rounds 1-4 (latency-
// bound short kernels). Per-b state (c2v 141 KB, tot 104 KB) stays L2-local;
// same-CU global write -> barrier -> read is coherent (vmcnt(0) drain before
// s_barrier).
//
// Per-b layouts (lane = z => coalesced, incl. shifted circulant access):
//   tot_b [N][Z] float        (104 KB)   belief for next iteration
//   c2v_b [E+1][Z] int8       (141.7 KB) value = 2*msg in [-15,15]; row E = 0
//   tables in LDS, built per block via LDS atomics (order-free: int sums)
//   out[it][b][z][n] written via LDS tile transpose (contiguous 68B segments)

#define ITERS 5
#define Nn 68
#define Mm 46
#define Zz 384
#define Ee 368
#define Bb 64
#define Kk 8          // edges per CN (E/M)
#define PADD 24       // padded max VN degree (graph max deg <= 24: rounds 1-4 exact)
#define BIGF 1e9f

#define SLICE   (Ee*Zz)          // 141,312 B per-b c2v slice (w/o dummy row)
#define SLICE_P (SLICE + Zz)     // 141,696 B incl. zeroed dummy row
#define NZ      (Nn*Zz)          // 26,112 elems
#define TOT_OFF 0
#define C2V_OFF (Bb*NZ*4)        // 6,684,672
// ws need: C2V_OFF + Bb*SLICE_P = 15,753,216 B (< round-1..4 usage, so it fits)

__global__ __launch_bounds__(1024) void fused_kernel(
    const float* __restrict__ xa,        // [B][N][Z]
    const float* __restrict__ cn_weight, // [ITERS]
    const int* __restrict__ edge_vn, const int* __restrict__ edge_shift,
    float* __restrict__ out,             // [ITERS][B][Z][N]
    float* __restrict__ tot_g, signed char* __restrict__ c2v_g)
{
    __shared__ int   s_ev[Ee];           // edge -> VN
    __shared__ int   s_sh[Ee];           // edge -> shift
    __shared__ int   s_deg[Nn];
    __shared__ int   s_voff[Nn * PADD];  // per-VN c2v byte offsets (dummy = SLICE)
    __shared__ float tile[17][Zz + 1];   // transpose staging, stride 385 (odd)

    const int b    = blockIdx.x;
    const int tid  = threadIdx.x;
    const int wave = tid >> 6;
    const int lane = tid & 63;
    const float* xa_b  = xa + (size_t)b * NZ;
    float*       tot_b = tot_g + (size_t)b * NZ;
    signed char* c2v_b = c2v_g + (size_t)b * SLICE_P;

    // ---- per-block table build (order within a VN is irrelevant: int sums) ----
    if (tid < Ee) { s_ev[tid] = edge_vn[tid]; s_sh[tid] = edge_shift[tid]; }
    else if (tid < Ee + Nn) s_deg[tid - Ee] = 0;
    __syncthreads();
    if (tid < Ee) {
        int n = s_ev[tid];
        int slot = atomicAdd(&s_deg[n], 1);
        if (slot < PADD) s_voff[n * PADD + slot] = tid * Zz;
    }
    if (tid >= 512 && tid < 512 + Zz / 4)              // zero the dummy row (384 B)
        ((int*)(c2v_b + SLICE))[tid - 512] = 0;
    __syncthreads();
    if (tid < Nn) {
        int d = s_deg[tid];
        if (d > PADD) { d = PADD; s_deg[tid] = PADD; }
        for (int j = d; j < PADD; j++) s_voff[tid * PADD + j] = SLICE; // dummy row
    }
    __syncthreads();

    #pragma unroll 1
    for (int it = 0; it < ITERS; it++) {
        const float w = cn_weight[it];
        const float* belief = it ? tot_b : xa_b;       // tot(it0) == xa, c2v == 0
        const bool sub = (it != 0);

        // ---- CN phase: min-sum over this b's 46 checks x 384 lifted rows ----
        for (int t = wave; t < Mm * 6; t += 16) {      // task = (cn, z-chunk of 64)
            int cn = t / 6;
            int zc = (t - cn * 6) * 64 + lane;         // CN-domain lifted row
            float v[Kk]; int off[Kk];
            float m1 = BIGF; unsigned sflip = 0u;
            #pragma unroll
            for (int k = 0; k < Kk; k++) {
                int e  = cn + k * Mm;                  // edge_cn = e % M
                int sh = s_sh[e], n = s_ev[e];         // wave-uniform (LDS bcast)
                int z  = zc - sh; z += (z >> 31) & Zz; // mod Z (VN-domain row)
                int o  = e * Zz + z;
                off[k] = o;
                float x = belief[n * Zz + z];
                if (sub) x -= 0.5f * (float)c2v_b[o];  // exact decode; skip at it0
                x = fminf(20.0f, fmaxf(-20.0f, x));    // allowed_llr_range
                v[k] = x;
                if (x < 0.0f) sflip ^= 1u;
                m1 = fminf(m1, fabsf(x));
            }
            float m2 = BIGF;                           // ref tie semantics
            #pragma unroll
            for (int k = 0; k < Kk; k++) {
                float mag = fabsf(v[k]);
                if (mag != m1) m2 = fminf(m2, mag);
            }
            #pragma unroll
            for (int k = 0; k < Kk; k++) {
                float mag  = fabsf(v[k]);
                float emin = (mag == m1) ? m2 : m1;
                unsigned neg = sflip ^ ((v[k] < 0.0f) ? 1u : 0u);
                float ext = neg ? -emin : emin;
                // _qms5(w*ext): forward == clip(rintf(2x)/2, +-7.5); store 2q int8
                float r = rintf(w * ext * 2.0f);
                r = fminf(15.0f, fmaxf(-15.0f, r));
                c2v_b[off[k]] = (signed char)(int)r;
            }
        }
        __syncthreads();                               // CN writes -> VN reads

        // ---- VN phase: 4 n-groups of 17; compute + tot store + out transpose ----
        float* outp = out + (size_t)it * (Bb * (size_t)NZ) + (size_t)b * NZ;
        for (int g = 0; g < 4; g++) {
            const int n0 = g * 17;
            for (int t = wave; t < 17 * 6; t += 16) {  // task = (n_local, z-chunk)
                int i = t / 6;
                int z = (t - i * 6) * 64 + lane;
                int n = n0 + i;
                int d = s_deg[n];                      // wave-uniform
                const int* vo = s_voff + n * PADD;
                int acc = 0;                           // int sum of 2*msg: exact
                #pragma unroll
                for (int j = 0; j < 8; j++) acc += (int)c2v_b[vo[j] + z];
                if (d > 8) {
                    #pragma unroll
                    for (int j = 8; j < 16; j++) acc += (int)c2v_b[vo[j] + z];
                }
                if (d > 16) {
                    #pragma unroll
                    for (int j = 16; j < PADD; j++) acc += (int)c2v_b[vo[j] + z];
                }
                float s = xa_b[n * Zz + z] + 0.5f * (float)acc;  // one rounding
                if (it < ITERS - 1) tot_b[n * Zz + z] = s;
                tile[i][z] = s;
            }
            __syncthreads();
            // out[b][z][n0..n0+16]: 17 consecutive dwords per z-row
            for (int idx = tid; idx < 17 * Zz; idx += 1024) {
                int zz = idx / 17;
                int nn = idx - zz * 17;
                outp[zz * Nn + n0 + nn] = tile[nn][zz];
            }
            __syncthreads();                           // before tile reuse
        }
    }
}

extern "C" void kernel_launch(void* const* d_in, const int* in_sizes, int n_in,
                              void* d_out, int out_size, void* d_ws, size_t ws_size,
                              hipStream_t stream) {
    const float* xa        = (const float*)d_in[0];  // [B][N][Z]
    const float* cn_weight = (const float*)d_in[1];  // [ITERS]
    const int*   edge_vn   = (const int*)d_in[2];    // [E]
    // d_in[3] = edge_cn: structurally e % M, not needed
    const int*   edge_shift= (const int*)d_in[4];    // [E]
    float* out = (float*)d_out;                      // [ITERS][B][Z][N]

    char* ws = (char*)d_ws;
    float*       tot_g = (float*)(ws + TOT_OFF);
    signed char* c2v_g = (signed char*)(ws + C2V_OFF);

    fused_kernel<<<Bb, 1024, 0, stream>>>(xa, cn_weight, edge_vn, edge_shift,
                                          out, tot_g, c2v_g);
}

// Round 6
// 294.761 us; speedup vs baseline: 1.3655x; 1.3655x over previous
//
#include <hip/hip_runtime.h>

// BoostedNeuralLDPCDecoder — MI355X HIP implementation (round 6)
//
// Round-5 fused kernel collapsed parallelism (64 blocks -> 334us). Reverted
// to round-4 multi-kernel structure (189us best). This round rewrites ONLY
// vn_kernel (clean A/B):
//  * c2v re-encoded as biased uint8 (2*msg+32; dummy row = 0x20): vn gathers
//    one aligned DWORD per edge covering 4 z, SWAR-accumulated in two
//    16-bit-lane accumulators (exact: <= 24*62 < 2^16). 4x fewer gather VMEM
//    instructions, 256B/wave-instr instead of 64B.
//  * degree-sorted VN permutation (built in init): waves see similar-degree
//    VNs -> d>8 / d>16 divergent paths nearly vanish.
//  * tables staged in LDS (16-lane broadcast reads); grid 64x12 = 768 blocks
//    (12 waves/CU); float4 xa/tot; direct dword out stores (L2 merges rows).
//
// Layouts:
//   tot  [N][B][Z] float      (6.68 MB)
//   c2v  [E+1][B][Z] uint8    (9.07 MB) biased 2*msg+32 in [2,62]; row E = 0x20
//   g_pn/g_pdeg[N], g_pvoff[N][24]  (degree-sorted; byte offsets e*ROWB)

#define ITERS 5
#define Nn 68
#define Mm 46
#define Zz 384
#define Ee 368
#define Bb 64
#define Kk 8          // edges per CN (E/M)
#define PADD 24       // padded max VN degree (verified: rounds 1-5 absmax 0)
#define BIGF 1e9f

#define ROWB (Bb*Zz)                     // 24,576 bytes per c2v edge-row
#define TOT_ELEMS (Nn*Bb*Zz)             // 1,671,168 floats
#define C2V_BYTES ((Ee+1)*ROWB)          // 9,068,544 bytes (incl. dummy row)
#define TOT_OFF   0
#define C2V_OFF   (TOT_ELEMS*4)          // 6,684,672
#define PN_OFF    (C2V_OFF + C2V_BYTES)  // 15,753,216
#define PD_OFF    (PN_OFF + Nn*4)
#define PVOFF_OFF (PD_OFF + Nn*4)
// ws need: PVOFF_OFF + Nn*PADD*4 = 15,760,288 bytes (~15.8 MB, same as r1-2)

__global__ __launch_bounds__(256) void init_kernel(
    const int* __restrict__ edge_vn, unsigned char* __restrict__ c2v,
    int* __restrict__ g_pn, int* __restrict__ g_pdeg, int* __restrict__ g_pvoff)
{
    if (blockIdx.x == 0) {
        // dummy row = biased zero (0x20); 24,576 B = 1536 int4
        int4* p = (int4*)(c2v + (size_t)Ee * ROWB);
        const int4 v = make_int4(0x20202020, 0x20202020, 0x20202020, 0x20202020);
        for (int i = threadIdx.x; i < ROWB / 16; i += 256) p[i] = v;
    } else {
        __shared__ int sev[Ee];
        __shared__ int deg[Nn];
        __shared__ int voff[Nn * PADD];
        __shared__ int perm[Nn];
        for (int t = threadIdx.x; t < Ee; t += 256) sev[t] = edge_vn[t];
        __syncthreads();
        int n = threadIdx.x;
        if (n < Nn) {
            int d = 0;
            for (int e = 0; e < Ee; e++)
                if (sev[e] == n && d < PADD) voff[n * PADD + (d++)] = e * ROWB;
            deg[n] = d;
            for (int j = d; j < PADD; j++) voff[n * PADD + j] = Ee * ROWB; // dummy
        }
        __syncthreads();
        if (threadIdx.x == 0) {
            // insertion sort VN ids by degree ascending (68 elems, once)
            for (int i = 0; i < Nn; i++) perm[i] = i;
            for (int i = 1; i < Nn; i++) {
                int p = perm[i], key = deg[p], j = i - 1;
                while (j >= 0 && deg[perm[j]] > key) { perm[j + 1] = perm[j]; j--; }
                perm[j + 1] = p;
            }
        }
        __syncthreads();
        if (threadIdx.x < Nn) {
            int src = perm[threadIdx.x];
            g_pn[threadIdx.x]   = src;
            g_pdeg[threadIdx.x] = deg[src];
            for (int j = 0; j < PADD; j++)
                g_pvoff[threadIdx.x * PADD + j] = voff[src * PADD + j];
        }
    }
}

__device__ __forceinline__ void minsum_store(
    const float v[Kk], const int off[Kk], float m1, unsigned sflip,
    float w, unsigned char* __restrict__ c2v)
{
    // min2 over entries whose |v| != min1 (reference tie semantics, BIG if none)
    float m2 = BIGF;
    #pragma unroll
    for (int k = 0; k < Kk; k++) {
        float mag = fabsf(v[k]);
        if (mag != m1) m2 = fminf(m2, mag);
    }
    #pragma unroll
    for (int k = 0; k < Kk; k++) {
        float mag  = fabsf(v[k]);
        float emin = (mag == m1) ? m2 : m1;
        unsigned neg = sflip ^ ((v[k] < 0.0f) ? 1u : 0u);  // csign * own_sign
        float ext = neg ? -emin : emin;
        // _qms5(w * ext): forward == clip(rintf(2*x)/2, +-7.5); store biased 2q
        float r = rintf(w * ext * 2.0f);
        r = fminf(15.0f, fmaxf(-15.0f, r));
        c2v[off[k]] = (unsigned char)((int)r + 32);
    }
}

__global__ __launch_bounds__(384) void cn0_kernel(
    const float* __restrict__ xa,        // [B][N][Z]; tot==xa, c2v==0 at it 0
    unsigned char* __restrict__ c2v,
    const int* __restrict__ edge_vn, const int* __restrict__ edge_shift,
    const float* __restrict__ cn_weight)
{
    const int cn = blockIdx.x;
    const int b  = blockIdx.y;
    const int zc = threadIdx.x;
    const float w = cn_weight[0];

    float v[Kk]; int off[Kk];
    float m1 = BIGF; unsigned sflip = 0u;

    #pragma unroll
    for (int k = 0; k < Kk; k++) {
        int e  = cn + k * Mm;
        int sh = edge_shift[e];          // block-uniform -> scalar load
        int n  = edge_vn[e];             // block-uniform
        int z  = zc - sh;
        z += (z >> 31) & Zz;             // mod Z
        off[k] = e * ROWB + b * Zz + z;
        float x = xa[(b * Nn + n) * Zz + z];      // belief; no c2v subtract at it 0
        x = fminf(20.0f, fmaxf(-20.0f, x));
        v[k] = x;
        if (x < 0.0f) sflip ^= 1u;
        m1 = fminf(m1, fabsf(x));
    }
    minsum_store(v, off, m1, sflip, w, c2v);
}

__global__ __launch_bounds__(384) void cn_kernel(
    const float* __restrict__ tot, unsigned char* __restrict__ c2v,
    const int* __restrict__ edge_vn, const int* __restrict__ edge_shift,
    const float* __restrict__ cn_weight, int it)
{
    const int cn = blockIdx.x;       // [0, M)
    const int b  = blockIdx.y;       // [0, B)
    const int zc = threadIdx.x;      // [0, Z) — CN-domain lifted row
    const float w = cn_weight[it];

    float v[Kk]; int off[Kk];
    float m1 = BIGF; unsigned sflip = 0u;

    #pragma unroll
    for (int k = 0; k < Kk; k++) {
        int e  = cn + k * Mm;        // edges of this check (edge_cn = e % M)
        int sh = edge_shift[e];      // block-uniform -> scalar load
        int n  = edge_vn[e];         // block-uniform
        int z  = zc - sh;
        z += (z >> 31) & Zz;         // mod Z
        int o = e * ROWB + b * Zz + z;
        off[k] = o;
        float t = tot[(n * Bb + b) * Zz + z];            // VN belief
        float x = t - 0.5f * (float)((int)c2v[o] - 32);  // exact biased decode
        x = fminf(20.0f, fmaxf(-20.0f, x));              // allowed_llr_range
        v[k] = x;
        if (x < 0.0f) sflip ^= 1u;
        m1 = fminf(m1, fabsf(x));
    }
    minsum_store(v, off, m1, sflip, w, c2v);
}

__global__ __launch_bounds__(256) void vn_kernel(
    const float* __restrict__ xa, const unsigned char* __restrict__ c2v,
    float* __restrict__ tot, float* __restrict__ out,
    const int* __restrict__ g_pn, const int* __restrict__ g_pdeg,
    const int* __restrict__ g_pvoff, int write_tot)
{
    __shared__ int s_voff[Nn * PADD];
    __shared__ int s_pn[Nn], s_pd[Nn];
    const int b  = blockIdx.x;
    const int z0 = blockIdx.y * 32;      // 32 z per block, 8 quad-slots
    for (int t = threadIdx.x; t < Nn * PADD; t += 256) s_voff[t] = g_pvoff[t];
    if (threadIdx.x < Nn) {
        s_pn[threadIdx.x] = g_pn[threadIdx.x];
        s_pd[threadIdx.x] = g_pdeg[threadIdx.x];
    }
    __syncthreads();

    // task m = (sorted-VN i, quad slot s); 16-lane groups share i (LDS bcast)
    for (int m = threadIdx.x; m < Nn * 8; m += 256) {
        int i = m >> 3, s = m & 7;
        int z = z0 + 4 * s;              // this thread owns z..z+3 (dword-aligned)
        int n = s_pd ? s_pn[i] : 0;      // real VN id
        int d = s_pd[i];
        const int* vo = s_voff + i * PADD;
        int base = b * Zz + z;
        // SWAR: two accumulators of 2x16-bit lanes; bytes are biased (2m+32)
        unsigned ae = 0u, ao = 0u;       // ae: z+0 (lo16), z+2 (hi16); ao: z+1, z+3
        #pragma unroll
        for (int j = 0; j < 8; j++) {
            unsigned u = *(const unsigned*)(c2v + (vo[j] + base));
            ae += u & 0x00FF00FFu;
            ao += (u >> 8) & 0x00FF00FFu;
        }
        int L = 8;
        if (d > 8) {
            L = 16;
            #pragma unroll
            for (int j = 8; j < 16; j++) {
                unsigned u = *(const unsigned*)(c2v + (vo[j] + base));
                ae += u & 0x00FF00FFu;
                ao += (u >> 8) & 0x00FF00FFu;
            }
            if (d > 16) {
                L = 24;
                #pragma unroll
                for (int j = 16; j < PADD; j++) {
                    unsigned u = *(const unsigned*)(c2v + (vo[j] + base));
                    ae += u & 0x00FF00FFu;
                    ao += (u >> 8) & 0x00FF00FFu;
                }
            }
        }
        // lane sums = sum(2*msg) + 32*L  (dummy rows contribute exactly bias)
        int bias = 32 * L;
        float4 x = *(const float4*)(xa + (size_t)(b * Nn + n) * Zz + z);
        float s0 = x.x + 0.5f * (float)((int)(ae & 0xFFFFu) - bias);
        float s1 = x.y + 0.5f * (float)((int)(ao & 0xFFFFu) - bias);
        float s2 = x.z + 0.5f * (float)((int)(ae >> 16) - bias);
        float s3 = x.w + 0.5f * (float)((int)(ao >> 16) - bias);
        if (write_tot)
            *(float4*)(tot + (n * Bb + b) * Zz + z) = make_float4(s0, s1, s2, s3);
        // out[b][z][n]: 4 dword scatter-stores, stride Nn; L2 merges the
        // block's full 272B rows (same-CU/XCD writes).
        float* op = out + ((size_t)b * Zz + z) * Nn + n;
        op[0] = s0; op[Nn] = s1; op[2 * Nn] = s2; op[3 * Nn] = s3;
    }
}

extern "C" void kernel_launch(void* const* d_in, const int* in_sizes, int n_in,
                              void* d_out, int out_size, void* d_ws, size_t ws_size,
                              hipStream_t stream) {
    const float* xa        = (const float*)d_in[0];  // [B][N][Z]
    const float* cn_weight = (const float*)d_in[1];  // [ITERS]
    const int*   edge_vn   = (const int*)d_in[2];    // [E]
    // d_in[3] = edge_cn: structurally e % M, not needed
    const int*   edge_shift= (const int*)d_in[4];    // [E]
    float* out = (float*)d_out;                      // [ITERS][B][Z][N]

    char* ws = (char*)d_ws;
    float*         tot     = (float*)(ws + TOT_OFF);
    unsigned char* c2v     = (unsigned char*)(ws + C2V_OFF);
    int*           g_pn    = (int*)(ws + PN_OFF);
    int*           g_pdeg  = (int*)(ws + PD_OFF);
    int*           g_pvoff = (int*)(ws + PVOFF_OFF);

    init_kernel<<<2, 256, 0, stream>>>(edge_vn, c2v, g_pn, g_pdeg, g_pvoff);

    for (int it = 0; it < ITERS; it++) {
        if (it == 0)
            cn0_kernel<<<dim3(Mm, Bb), 384, 0, stream>>>(xa, c2v, edge_vn,
                                                         edge_shift, cn_weight);
        else
            cn_kernel<<<dim3(Mm, Bb), 384, 0, stream>>>(tot, c2v, edge_vn,
                                                        edge_shift, cn_weight, it);
        vn_kernel<<<dim3(Bb, Zz / 32), 256, 0, stream>>>(
            xa, c2v, tot, out + (size_t)it * Bb * Zz * Nn,
            g_pn, g_pdeg, g_pvoff, (it != ITERS - 1) ? 1 : 0);
    }
}

// Round 7
// 203.390 us; speedup vs baseline: 1.9789x; 1.4492x over previous
//
#include <hip/hip_runtime.h>

// BoostedNeuralLDPCDecoder — MI355X HIP implementation (round 7)
//
// Round-6 post-mortem: init_kernel was 122.8us (41% of total!) — the
// single-threaded insertion sort on thread 0 serialized ~2300 dependent LDS
// accesses at ~120cyc each. The SWAR vn rewrite itself was a ~12us win
// (total-init = 172 vs round-4 ~184).
// Round-7 change: ONLY init — parallel degree-rank (each thread computes its
// VN's rank with 68 independent LDS reads, scatters its table row there).
// Identical permutation, no serial sort.
//
// Layouts:
//   tot  [N][B][Z] float      (6.68 MB)
//   c2v  [E+1][B][Z] uint8    (9.07 MB) biased 2*msg+32 in [2,62]; row E = 0x20
//   g_pn/g_pdeg[N], g_pvoff[N][24]  (degree-sorted; byte offsets e*ROWB)

#define ITERS 5
#define Nn 68
#define Mm 46
#define Zz 384
#define Ee 368
#define Bb 64
#define Kk 8          // edges per CN (E/M)
#define PADD 24       // padded max VN degree (verified: rounds 1-6 absmax 0)
#define BIGF 1e9f

#define ROWB (Bb*Zz)                     // 24,576 bytes per c2v edge-row
#define TOT_ELEMS (Nn*Bb*Zz)             // 1,671,168 floats
#define C2V_BYTES ((Ee+1)*ROWB)          // 9,068,544 bytes (incl. dummy row)
#define TOT_OFF   0
#define C2V_OFF   (TOT_ELEMS*4)          // 6,684,672
#define PN_OFF    (C2V_OFF + C2V_BYTES)  // 15,753,216
#define PD_OFF    (PN_OFF + Nn*4)
#define PVOFF_OFF (PD_OFF + Nn*4)
// ws need: PVOFF_OFF + Nn*PADD*4 = 15,760,288 bytes (~15.8 MB)

__global__ __launch_bounds__(256) void init_kernel(
    const int* __restrict__ edge_vn, unsigned char* __restrict__ c2v,
    int* __restrict__ g_pn, int* __restrict__ g_pdeg, int* __restrict__ g_pvoff)
{
    if (blockIdx.x == 0) {
        // dummy row = biased zero (0x20); 24,576 B = 1536 int4
        int4* p = (int4*)(c2v + (size_t)Ee * ROWB);
        const int4 v = make_int4(0x20202020, 0x20202020, 0x20202020, 0x20202020);
        for (int i = threadIdx.x; i < ROWB / 16; i += 256) p[i] = v;
    } else {
        __shared__ int sev[Ee];
        __shared__ int deg[Nn];
        __shared__ int voff[Nn * PADD];
        for (int t = threadIdx.x; t < Ee; t += 256) sev[t] = edge_vn[t];
        __syncthreads();
        const int n = threadIdx.x;
        if (n < Nn) {
            int d = 0;
            for (int e = 0; e < Ee; e++)
                if (sev[e] == n && d < PADD) voff[n * PADD + (d++)] = e * ROWB;
            deg[n] = d;
            for (int j = d; j < PADD; j++) voff[n * PADD + j] = Ee * ROWB; // dummy
        }
        __syncthreads();
        if (n < Nn) {
            // parallel degree-rank (stable: tie-break by id) — replaces the
            // serial insertion sort that cost 122.8us in round 6
            const int d = deg[n];
            int rank = 0;
            #pragma unroll 4
            for (int m = 0; m < Nn; m++) {
                int dm = deg[m];
                rank += (dm < d || (dm == d && m < n)) ? 1 : 0;
            }
            g_pn[rank]   = n;
            g_pdeg[rank] = d;
            for (int j = 0; j < PADD; j++)
                g_pvoff[rank * PADD + j] = voff[n * PADD + j];
        }
    }
}

__device__ __forceinline__ void minsum_store(
    const float v[Kk], const int off[Kk], float m1, unsigned sflip,
    float w, unsigned char* __restrict__ c2v)
{
    // min2 over entries whose |v| != min1 (reference tie semantics, BIG if none)
    float m2 = BIGF;
    #pragma unroll
    for (int k = 0; k < Kk; k++) {
        float mag = fabsf(v[k]);
        if (mag != m1) m2 = fminf(m2, mag);
    }
    #pragma unroll
    for (int k = 0; k < Kk; k++) {
        float mag  = fabsf(v[k]);
        float emin = (mag == m1) ? m2 : m1;
        unsigned neg = sflip ^ ((v[k] < 0.0f) ? 1u : 0u);  // csign * own_sign
        float ext = neg ? -emin : emin;
        // _qms5(w * ext): forward == clip(rintf(2*x)/2, +-7.5); store biased 2q
        float r = rintf(w * ext * 2.0f);
        r = fminf(15.0f, fmaxf(-15.0f, r));
        c2v[off[k]] = (unsigned char)((int)r + 32);
    }
}

__global__ __launch_bounds__(384) void cn0_kernel(
    const float* __restrict__ xa,        // [B][N][Z]; tot==xa, c2v==0 at it 0
    unsigned char* __restrict__ c2v,
    const int* __restrict__ edge_vn, const int* __restrict__ edge_shift,
    const float* __restrict__ cn_weight)
{
    const int cn = blockIdx.x;
    const int b  = blockIdx.y;
    const int zc = threadIdx.x;
    const float w = cn_weight[0];

    float v[Kk]; int off[Kk];
    float m1 = BIGF; unsigned sflip = 0u;

    #pragma unroll
    for (int k = 0; k < Kk; k++) {
        int e  = cn + k * Mm;
        int sh = edge_shift[e];          // block-uniform -> scalar load
        int n  = edge_vn[e];             // block-uniform
        int z  = zc - sh;
        z += (z >> 31) & Zz;             // mod Z
        off[k] = e * ROWB + b * Zz + z;
        float x = xa[(b * Nn + n) * Zz + z];      // belief; no c2v subtract at it 0
        x = fminf(20.0f, fmaxf(-20.0f, x));
        v[k] = x;
        if (x < 0.0f) sflip ^= 1u;
        m1 = fminf(m1, fabsf(x));
    }
    minsum_store(v, off, m1, sflip, w, c2v);
}

__global__ __launch_bounds__(384) void cn_kernel(
    const float* __restrict__ tot, unsigned char* __restrict__ c2v,
    const int* __restrict__ edge_vn, const int* __restrict__ edge_shift,
    const float* __restrict__ cn_weight, int it)
{
    const int cn = blockIdx.x;       // [0, M)
    const int b  = blockIdx.y;       // [0, B)
    const int zc = threadIdx.x;      // [0, Z) — CN-domain lifted row
    const float w = cn_weight[it];

    float v[Kk]; int off[Kk];
    float m1 = BIGF; unsigned sflip = 0u;

    #pragma unroll
    for (int k = 0; k < Kk; k++) {
        int e  = cn + k * Mm;        // edges of this check (edge_cn = e % M)
        int sh = edge_shift[e];      // block-uniform -> scalar load
        int n  = edge_vn[e];         // block-uniform
        int z  = zc - sh;
        z += (z >> 31) & Zz;         // mod Z
        int o = e * ROWB + b * Zz + z;
        off[k] = o;
        float t = tot[(n * Bb + b) * Zz + z];            // VN belief
        float x = t - 0.5f * (float)((int)c2v[o] - 32);  // exact biased decode
        x = fminf(20.0f, fmaxf(-20.0f, x));              // allowed_llr_range
        v[k] = x;
        if (x < 0.0f) sflip ^= 1u;
        m1 = fminf(m1, fabsf(x));
    }
    minsum_store(v, off, m1, sflip, w, c2v);
}

__global__ __launch_bounds__(256) void vn_kernel(
    const float* __restrict__ xa, const unsigned char* __restrict__ c2v,
    float* __restrict__ tot, float* __restrict__ out,
    const int* __restrict__ g_pn, const int* __restrict__ g_pdeg,
    const int* __restrict__ g_pvoff, int write_tot)
{
    __shared__ int s_voff[Nn * PADD];
    __shared__ int s_pn[Nn], s_pd[Nn];
    const int b  = blockIdx.x;
    const int z0 = blockIdx.y * 32;      // 32 z per block, 8 quad-slots
    for (int t = threadIdx.x; t < Nn * PADD; t += 256) s_voff[t] = g_pvoff[t];
    if (threadIdx.x < Nn) {
        s_pn[threadIdx.x] = g_pn[threadIdx.x];
        s_pd[threadIdx.x] = g_pdeg[threadIdx.x];
    }
    __syncthreads();

    // task m = (sorted-VN i, quad slot s); 8-thread groups share i (LDS bcast);
    // degree-sorted order keeps the d>8/d>16 paths wave-uniform.
    for (int m = threadIdx.x; m < Nn * 8; m += 256) {
        int i = m >> 3, s = m & 7;
        int z = z0 + 4 * s;              // this thread owns z..z+3 (dword-aligned)
        int n = s_pn[i];                 // real VN id
        int d = s_pd[i];
        const int* vo = s_voff + i * PADD;
        int base = b * Zz + z;
        // SWAR: two accumulators of 2x16-bit lanes; bytes are biased (2m+32)
        unsigned ae = 0u, ao = 0u;       // ae: z+0 (lo16), z+2 (hi16); ao: z+1, z+3
        #pragma unroll
        for (int j = 0; j < 8; j++) {
            unsigned u = *(const unsigned*)(c2v + (vo[j] + base));
            ae += u & 0x00FF00FFu;
            ao += (u >> 8) & 0x00FF00FFu;
        }
        int L = 8;
        if (d > 8) {
            L = 16;
            #pragma unroll
            for (int j = 8; j < 16; j++) {
                unsigned u = *(const unsigned*)(c2v + (vo[j] + base));
                ae += u & 0x00FF00FFu;
                ao += (u >> 8) & 0x00FF00FFu;
            }
            if (d > 16) {
                L = 24;
                #pragma unroll
                for (int j = 16; j < PADD; j++) {
                    unsigned u = *(const unsigned*)(c2v + (vo[j] + base));
                    ae += u & 0x00FF00FFu;
                    ao += (u >> 8) & 0x00FF00FFu;
                }
            }
        }
        // lane sums = sum(2*msg) + 32*L  (dummy rows contribute exactly bias)
        int bias = 32 * L;
        float4 x = *(const float4*)(xa + (size_t)(b * Nn + n) * Zz + z);
        float s0 = x.x + 0.5f * (float)((int)(ae & 0xFFFFu) - bias);
        float s1 = x.y + 0.5f * (float)((int)(ao & 0xFFFFu) - bias);
        float s2 = x.z + 0.5f * (float)((int)(ae >> 16) - bias);
        float s3 = x.w + 0.5f * (float)((int)(ao >> 16) - bias);
        if (write_tot)
            *(float4*)(tot + (n * Bb + b) * Zz + z) = make_float4(s0, s1, s2, s3);
        // out[b][z][n]: 4 dword scatter-stores, stride Nn; L2 merges the
        // block's full 272B rows.
        float* op = out + ((size_t)b * Zz + z) * Nn + n;
        op[0] = s0; op[Nn] = s1; op[2 * Nn] = s2; op[3 * Nn] = s3;
    }
}

extern "C" void kernel_launch(void* const* d_in, const int* in_sizes, int n_in,
                              void* d_out, int out_size, void* d_ws, size_t ws_size,
                              hipStream_t stream) {
    const float* xa        = (const float*)d_in[0];  // [B][N][Z]
    const float* cn_weight = (const float*)d_in[1];  // [ITERS]
    const int*   edge_vn   = (const int*)d_in[2];    // [E]
    // d_in[3] = edge_cn: structurally e % M, not needed
    const int*   edge_shift= (const int*)d_in[4];    // [E]
    float* out = (float*)d_out;                      // [ITERS][B][Z][N]

    char* ws = (char*)d_ws;
    float*         tot     = (float*)(ws + TOT_OFF);
    unsigned char* c2v     = (unsigned char*)(ws + C2V_OFF);
    int*           g_pn    = (int*)(ws + PN_OFF);
    int*           g_pdeg  = (int*)(ws + PD_OFF);
    int*           g_pvoff = (int*)(ws + PVOFF_OFF);

    init_kernel<<<2, 256, 0, stream>>>(edge_vn, c2v, g_pn, g_pdeg, g_pvoff);

    for (int it = 0; it < ITERS; it++) {
        if (it == 0)
            cn0_kernel<<<dim3(Mm, Bb), 384, 0, stream>>>(xa, c2v, edge_vn,
                                                         edge_shift, cn_weight);
        else
            cn_kernel<<<dim3(Mm, Bb), 384, 0, stream>>>(tot, c2v, edge_vn,
                                                        edge_shift, cn_weight, it);
        vn_kernel<<<dim3(Bb, Zz / 32), 256, 0, stream>>>(
            xa, c2v, tot, out + (size_t)it * Bb * Zz * Nn,
            g_pn, g_pdeg, g_pvoff, (it != ITERS - 1) ? 1 : 0);
    }
}